// Round 1
// baseline (2003.688 us; speedup 1.0000x reference)
//
#include <hip/hip_runtime.h>
#include <hip/hip_bf16.h>

// Problem constants (fixed by the reference file)
constexpr int B_ = 4;
constexpr int M_ = 8192;          // nodes per graph
constexpr int N_ = B_ * M_;       // 32768
constexpr int K_ = 16;            // START_K, K_INCREMENT = 0
constexpr int NX_ = N_ * 64;      // x element count = 2097152

// Flat f32 output layout (outputs concatenated in return order)
constexpr long long OFF_X      = 0;                         // x        [N,64]
constexpr long long OFF_POS    = OFF_X + NX_;               // pos_p    [N,2]
constexpr long long OFF_EI_SRC = OFF_POS + 2LL * N_;        // edge_index row 0 (src) [N*K]
constexpr long long OFF_EI_TGT = OFF_EI_SRC + 1LL * N_ * K_;// edge_index row 1 (tgt) [N*K]
constexpr long long OFF_W      = OFF_EI_TGT + 1LL * N_ * K_;// edge_weight [N*K]
constexpr long long OFF_BATCH  = OFF_W + 1LL * N_ * K_;     // batch [N]
constexpr long long OFF_PERM   = OFF_BATCH + N_;            // perm  [N]
constexpr long long OFF_SCORE  = OFF_PERM + N_;             // score [N]

// ---------------------------------------------------------------------------
// Pass-through copies + pos gather + tgt row of edge_index
// ---------------------------------------------------------------------------
__global__ __launch_bounds__(256) void misc_kernel(
    const float* __restrict__ x, const float* __restrict__ pos,
    const int* __restrict__ batch, const int* __restrict__ perm,
    const float* __restrict__ score, float* __restrict__ out) {
  const int i = blockIdx.x * blockDim.x + threadIdx.x;
  if (i < NX_) out[OFF_X + i] = x[i];
  if (i < N_) {
    const int p = perm[i];
    out[OFF_POS + 2 * i]     = pos[2 * p];
    out[OFF_POS + 2 * i + 1] = pos[2 * p + 1];
    out[OFF_BATCH + i] = (float)batch[i];
    out[OFF_PERM + i]  = (float)p;
    out[OFF_SCORE + i] = score[i];
  }
  if (i < N_ * K_) out[OFF_EI_TGT + i] = (float)(i >> 4);  // tgt = repeat(arange(N), k)
}

// ---------------------------------------------------------------------------
// Brute-force exact KNN, one thread per query, graph positions staged in LDS.
// Key = (f32 bits of d2 << 32) | local_idx  -> ascending u64 == top_k order
// with jax.lax.top_k's stable lower-index-first tie-break.
// ---------------------------------------------------------------------------
__global__ __launch_bounds__(256) void knn_kernel(
    const float* __restrict__ pos, const int* __restrict__ perm,
    float* __restrict__ out, unsigned int* __restrict__ maxbits) {
  __shared__ float2 sp[M_];  // 64 KiB
  const int g    = blockIdx.x >> 5;   // 32 blocks of 256 queries per graph
  const int base = g * M_;

  for (int t = threadIdx.x; t < M_; t += 256) {
    const int p = perm[base + t];
    sp[t] = make_float2(pos[2 * p], pos[2 * p + 1]);
  }
  __syncthreads();

  const int ql = ((blockIdx.x & 31) << 8) | threadIdx.x;  // local query id
  const float qx = sp[ql].x, qy = sp[ql].y;

  unsigned long long lst[K_];  // ascending sorted; lst[15] is current worst
#pragma unroll
  for (int s = 0; s < K_; ++s) lst[s] = ~0ull;

  auto insert_key = [&](unsigned long long key) {
#pragma unroll
    for (int s = 0; s < K_; ++s) {
      const unsigned long long a = lst[s];
      const bool lt = key < a;
      lst[s] = lt ? key : a;
      key    = lt ? a : key;
    }
  };

  const float4* sp4 = reinterpret_cast<const float4*>(sp);
#pragma unroll 4
  for (int jj = 0; jj < M_ / 2; ++jj) {
    const float4 c = sp4[jj];  // two candidate points; uniform addr -> broadcast
    {
      const float dx = __fsub_rn(c.x, qx), dy = __fsub_rn(c.y, qy);
      const float d2 = __fadd_rn(__fmul_rn(dx, dx), __fmul_rn(dy, dy));
      const unsigned long long key =
          ((unsigned long long)__float_as_uint(d2) << 32) | (unsigned)(2 * jj);
      if (key < lst[K_ - 1]) insert_key(key);
    }
    {
      const float dx = __fsub_rn(c.z, qx), dy = __fsub_rn(c.w, qy);
      const float d2 = __fadd_rn(__fmul_rn(dx, dx), __fmul_rn(dy, dy));
      const unsigned long long key =
          ((unsigned long long)__float_as_uint(d2) << 32) | (unsigned)(2 * jj + 1);
      if (key < lst[K_ - 1]) insert_key(key);
    }
  }

  const int gq = base + ql;  // global node id
  float mx = 0.f;
#pragma unroll
  for (int s = 0; s < K_; ++s) {
    const unsigned j  = (unsigned)(lst[s] & 0xffffffffu);
    const float    d2 = __uint_as_float((unsigned)(lst[s] >> 32));
    const float    d  = sqrtf(d2);  // d2 >= 0 always; matches sqrt(max(d2,0))
    out[OFF_EI_SRC + (long long)gq * K_ + s] = (float)(base + (int)j);
    out[OFF_W + (long long)gq * K_ + s]      = d;  // unnormalized for now
    mx = fmaxf(mx, d);
  }

  // wave-level max reduce, then one atomic per wave (f32 bits monotone for >=0)
#pragma unroll
  for (int o = 32; o; o >>= 1) mx = fmaxf(mx, __shfl_xor(mx, o));
  if ((threadIdx.x & 63) == 0) atomicMax(maxbits, __float_as_uint(mx));
}

// ---------------------------------------------------------------------------
// weight[i] = dist[i] / max(dist)
// ---------------------------------------------------------------------------
__global__ __launch_bounds__(256) void norm_kernel(float* __restrict__ out,
                                                   const unsigned int* __restrict__ maxbits) {
  const float m = __uint_as_float(*maxbits);
  const int i = blockIdx.x * blockDim.x + threadIdx.x;
  if (i < N_ * K_) out[OFF_W + i] = out[OFF_W + i] / m;
}

extern "C" void kernel_launch(void* const* d_in, const int* in_sizes, int n_in,
                              void* d_out, int out_size, void* d_ws, size_t ws_size,
                              hipStream_t stream) {
  const float* x     = (const float*)d_in[0];
  const float* pos   = (const float*)d_in[1];
  // d_in[2] edge_index, d_in[3] edge_weight, d_in[7] i : unused by the output
  const int*   batch = (const int*)d_in[4];
  const int*   perm  = (const int*)d_in[5];
  const float* score = (const float*)d_in[6];
  float* out = (float*)d_out;
  unsigned int* maxbits = (unsigned int*)d_ws;

  hipMemsetAsync(d_ws, 0, 4, stream);  // atomic-max accumulator = 0

  hipLaunchKernelGGL(misc_kernel, dim3(NX_ / 256), dim3(256), 0, stream,
                     x, pos, batch, perm, score, out);
  hipLaunchKernelGGL(knn_kernel, dim3(N_ / 256), dim3(256), 0, stream,
                     pos, perm, out, maxbits);
  hipLaunchKernelGGL(norm_kernel, dim3((N_ * K_) / 256), dim3(256), 0, stream,
                     out, maxbits);
}

// Round 2
// 215.664 us; speedup vs baseline: 9.2908x; 9.2908x over previous
//
#include <hip/hip_runtime.h>
#include <hip/hip_bf16.h>

// Problem constants (fixed by the reference file)
constexpr int B_ = 4;
constexpr int M_ = 8192;          // nodes per graph
constexpr int N_ = B_ * M_;       // 32768
constexpr int K_ = 16;            // START_K, K_INCREMENT = 0
constexpr int NX_ = N_ * 64;      // x element count = 2097152
constexpr int G_ = 16;            // grid cells per axis per graph
constexpr int C_ = G_ * G_;       // 256 cells/graph
constexpr int CT_ = B_ * C_;      // 1024 cells total
constexpr float CW_ = 62.5f;      // cell width = 1000/16, exactly representable
constexpr float INVW_ = 0.016f;   // ~1/62.5 (only used for binning; slop covered by eps)

// Flat f32 output layout (outputs concatenated in return order)
constexpr long long OFF_X      = 0;                          // x        [N,64]
constexpr long long OFF_POS    = OFF_X + NX_;                // pos_p    [N,2]
constexpr long long OFF_EI_SRC = OFF_POS + 2LL * N_;         // edge_index row0 (src) [N*K]
constexpr long long OFF_EI_TGT = OFF_EI_SRC + 1LL * N_ * K_; // edge_index row1 (tgt) [N*K]
constexpr long long OFF_W      = OFF_EI_TGT + 1LL * N_ * K_; // edge_weight [N*K]
constexpr long long OFF_BATCH  = OFF_W + 1LL * N_ * K_;      // batch [N]
constexpr long long OFF_PERM   = OFF_BATCH + N_;             // perm  [N]
constexpr long long OFF_SCORE  = OFF_PERM + N_;              // score [N]

// Workspace layout (bytes)
constexpr size_t WS_COUNTS  = 0;                         // int[1024]
constexpr size_t WS_STARTS  = 4096;                      // int[1024]
constexpr size_t WS_PTR     = 8192;                      // int[1024]
constexpr size_t WS_MAXBITS = 12288;                     // uint
constexpr size_t WS_CELLID  = 16384;                     // int[N]
constexpr size_t WS_POSP    = WS_CELLID + 4ull * N_;     // float2[N]
constexpr size_t WS_BPOS    = WS_POSP + 8ull * N_;       // float2[N]
constexpr size_t WS_BLIDX   = WS_BPOS + 8ull * N_;       // int[N]
constexpr size_t WS_BQ      = WS_BLIDX + 4ull * N_;      // int[N]

// ---------------------------------------------------------------------------
// Pass-through copies + pos gather + tgt row. 524288 threads exactly.
// ---------------------------------------------------------------------------
__global__ __launch_bounds__(256) void misc_kernel(
    const float* __restrict__ x, const int* __restrict__ batch,
    const float* __restrict__ score, const float2* __restrict__ pos_pw,
    const int* __restrict__ perm, float* __restrict__ out) {
  const int i = blockIdx.x * blockDim.x + threadIdx.x;
  reinterpret_cast<float4*>(out + OFF_X)[i] =
      reinterpret_cast<const float4*>(x)[i];                       // x copy, 16B/lane
  if (i < N_) {
    const float2 p = pos_pw[i];
    out[OFF_POS + 2 * i]     = p.x;
    out[OFF_POS + 2 * i + 1] = p.y;
    out[OFF_BATCH + i] = (float)batch[i];
    out[OFF_PERM + i]  = (float)perm[i];
    out[OFF_SCORE + i] = score[i];
  }
  out[OFF_EI_TGT + i] = (float)(i >> 4);  // tgt = repeat(arange(N), k); range == N*K
}

// ---------------------------------------------------------------------------
// Bin pass 1: gather pooled positions, compute cell ids, count per cell.
// ---------------------------------------------------------------------------
__global__ __launch_bounds__(256) void count_kernel(
    const float* __restrict__ pos, const int* __restrict__ perm,
    float2* __restrict__ pos_pw, int* __restrict__ cellid,
    int* __restrict__ counts) {
  const int i = blockIdx.x * blockDim.x + threadIdx.x;
  if (i >= N_) return;
  const int p = perm[i];
  const float px = pos[2 * p], py = pos[2 * p + 1];
  pos_pw[i] = make_float2(px, py);
  int cx = (int)(px * INVW_); cx = cx < 0 ? 0 : (cx > G_ - 1 ? G_ - 1 : cx);
  int cy = (int)(py * INVW_); cy = cy < 0 ? 0 : (cy > G_ - 1 ? G_ - 1 : cy);
  const int cell = (i >> 13) * C_ + (cy << 4) + cx;
  cellid[i] = cell;
  atomicAdd(&counts[cell], 1);
}

// ---------------------------------------------------------------------------
// Exclusive prefix sum over the 1024 cells (graph-major -> per-graph slabs).
// ---------------------------------------------------------------------------
__global__ __launch_bounds__(1024) void scan_kernel(
    const int* __restrict__ counts, int* __restrict__ starts,
    int* __restrict__ cellptr) {
  __shared__ int buf[CT_];
  const int t = threadIdx.x;
  const int v = counts[t];
  buf[t] = v;
  __syncthreads();
  for (int off = 1; off < CT_; off <<= 1) {
    const int add = (t >= off) ? buf[t - off] : 0;
    __syncthreads();
    buf[t] += add;
    __syncthreads();
  }
  const int excl = buf[t] - v;
  starts[t] = excl;
  cellptr[t] = excl;
}

// ---------------------------------------------------------------------------
// Bin pass 2: scatter nodes into binned arrays (order nondeterministic, but
// results are order-independent thanks to the (d2,idx) key tie-break).
// ---------------------------------------------------------------------------
__global__ __launch_bounds__(256) void scatter_kernel(
    const float2* __restrict__ pos_pw, const int* __restrict__ cellid,
    int* __restrict__ cellptr, float2* __restrict__ bpos,
    int* __restrict__ blidx, int* __restrict__ bq) {
  const int i = blockIdx.x * blockDim.x + threadIdx.x;
  if (i >= N_) return;
  const int c = cellid[i];
  const int s = atomicAdd(&cellptr[c], 1);
  bpos[s] = pos_pw[i];
  blidx[s] = i & (M_ - 1);  // local index within graph (tie-break key)
  bq[s] = i;                // global pooled node id
}

// ---------------------------------------------------------------------------
// Exact KNN via expanding Chebyshev rings over the grid. One thread per
// binned slot (so a wave's 64 queries share ~2 cells -> coherent loops).
// Key = (f32 bits of d2 << 32) | local_idx; ascending == top_k order.
// ---------------------------------------------------------------------------
__global__ __launch_bounds__(64) void knn_grid_kernel(
    const int* __restrict__ starts, const int* __restrict__ counts,
    const float2* __restrict__ bpos, const int* __restrict__ blidx,
    const int* __restrict__ bq, const int* __restrict__ cellid,
    float* __restrict__ out, unsigned int* __restrict__ maxbits) {
  const int s = blockIdx.x * 64 + threadIdx.x;  // binned slot == query
  const int gq = bq[s];                         // global pooled node id
  const int g = gq >> 13;                       // graph
  const int cellbase = g * C_;
  const int lcell = cellid[gq] - cellbase;
  const int qcx = lcell & (G_ - 1), qcy = lcell >> 4;
  const float2 qp = bpos[s];
  const float qx = qp.x, qy = qp.y;

  unsigned long long lst[K_];
#pragma unroll
  for (int t = 0; t < K_; ++t) lst[t] = ~0ull;

  auto insert_key = [&](unsigned long long key) {
#pragma unroll
    for (int t = 0; t < K_; ++t) {
      const unsigned long long a = lst[t];
      const bool lt = key < a;
      lst[t] = lt ? key : a;
      key = lt ? a : key;
    }
  };

  auto scan_cell = [&](int cx, int cy) {
    const int cell = cellbase + (cy << 4) + cx;
    const int s0 = starts[cell];
    const int e0 = s0 + counts[cell];
    for (int j = s0; j < e0; ++j) {
      const float2 bp = bpos[j];
      const float dx = __fsub_rn(bp.x, qx), dy = __fsub_rn(bp.y, qy);
      const float d2 = __fadd_rn(__fmul_rn(dx, dx), __fmul_rn(dy, dy));
      const unsigned db = __float_as_uint(d2);
      if (db <= (unsigned)(lst[K_ - 1] >> 32)) {  // quick f32-bits filter (incl ties)
        const unsigned long long key =
            ((unsigned long long)db << 32) | (unsigned)blidx[j];
        if (key < lst[K_ - 1]) insert_key(key);
      }
    }
  };

  for (int c = 0; c < G_; ++c) {
    const int x0 = qcx - c, x1 = qcx + c;
    const int y0 = qcy - c, y1 = qcy + c;
    const int xs = x0 < 0 ? 0 : x0, xe = x1 > G_ - 1 ? G_ - 1 : x1;
    const int ys = y0 < 0 ? 0 : y0, ye = y1 > G_ - 1 ? G_ - 1 : y1;
    for (int y = ys; y <= ye; ++y) {
      if (y == y0 || y == y1) {
        for (int x = xs; x <= xe; ++x) scan_cell(x, y);  // full row (top/bottom)
      } else {
        if (x0 >= 0) scan_cell(x0, y);
        if (x1 <= G_ - 1) scan_cell(x1, y);
      }
    }
    // Unscanned region has Chebyshev >= c+1 -> true distance > c*CW_.
    // eps 0.01 conservatively covers cell-assignment float slop (~1e-4).
    if (c >= 1 && lst[K_ - 1] != ~0ull) {
      const float bound = (float)c * CW_ - 0.01f;
      const float kth = __uint_as_float((unsigned)(lst[K_ - 1] >> 32));
      if (bound * bound > kth) break;
    }
  }

  const int base = g << 13;
  float mx = 0.f;
#pragma unroll
  for (int t = 0; t < K_; ++t) {
    const unsigned j = (unsigned)(lst[t] & 0xffffffffu);
    const float d2 = __uint_as_float((unsigned)(lst[t] >> 32));
    const float d = sqrtf(d2);
    out[OFF_EI_SRC + (long long)gq * K_ + t] = (float)(base + (int)j);
    out[OFF_W + (long long)gq * K_ + t] = d;  // unnormalized
    mx = fmaxf(mx, d);
  }
#pragma unroll
  for (int o = 32; o; o >>= 1) mx = fmaxf(mx, __shfl_xor(mx, o));
  if ((threadIdx.x & 63) == 0) atomicMax(maxbits, __float_as_uint(mx));
}

// ---------------------------------------------------------------------------
// weight[i] = dist[i] / max(dist)
// ---------------------------------------------------------------------------
__global__ __launch_bounds__(256) void norm_kernel(
    float* __restrict__ out, const unsigned int* __restrict__ maxbits) {
  const float m = __uint_as_float(*maxbits);
  const int i = blockIdx.x * blockDim.x + threadIdx.x;
  out[OFF_W + i] = out[OFF_W + i] / m;  // grid sized exactly N*K
}

extern "C" void kernel_launch(void* const* d_in, const int* in_sizes, int n_in,
                              void* d_out, int out_size, void* d_ws, size_t ws_size,
                              hipStream_t stream) {
  const float* x     = (const float*)d_in[0];
  const float* pos   = (const float*)d_in[1];
  const int*   batch = (const int*)d_in[4];
  const int*   perm  = (const int*)d_in[5];
  const float* score = (const float*)d_in[6];
  float* out = (float*)d_out;

  char* ws = (char*)d_ws;
  int*          counts  = (int*)(ws + WS_COUNTS);
  int*          startsA = (int*)(ws + WS_STARTS);
  int*          cellptr = (int*)(ws + WS_PTR);
  unsigned int* maxbits = (unsigned int*)(ws + WS_MAXBITS);
  int*          cellid  = (int*)(ws + WS_CELLID);
  float2*       pos_pw  = (float2*)(ws + WS_POSP);
  float2*       bpos    = (float2*)(ws + WS_BPOS);
  int*          blidx   = (int*)(ws + WS_BLIDX);
  int*          bq      = (int*)(ws + WS_BQ);

  hipMemsetAsync(counts, 0, CT_ * sizeof(int), stream);
  hipMemsetAsync(maxbits, 0, sizeof(unsigned int), stream);

  hipLaunchKernelGGL(count_kernel, dim3(N_ / 256), dim3(256), 0, stream,
                     pos, perm, pos_pw, cellid, counts);
  hipLaunchKernelGGL(misc_kernel, dim3(NX_ / 4 / 256), dim3(256), 0, stream,
                     x, batch, score, pos_pw, perm, out);
  hipLaunchKernelGGL(scan_kernel, dim3(1), dim3(CT_), 0, stream,
                     counts, startsA, cellptr);
  hipLaunchKernelGGL(scatter_kernel, dim3(N_ / 256), dim3(256), 0, stream,
                     pos_pw, cellid, cellptr, bpos, blidx, bq);
  hipLaunchKernelGGL(knn_grid_kernel, dim3(N_ / 64), dim3(64), 0, stream,
                     startsA, counts, bpos, blidx, bq, cellid, out, maxbits);
  hipLaunchKernelGGL(norm_kernel, dim3((N_ * K_) / 256), dim3(256), 0, stream,
                     out, maxbits);
}